// Round 4
// baseline (448.503 us; speedup 1.0000x reference)
//
#include <hip/hip_runtime.h>

// GNN: 2x GCNConv(relu) + mean-pool + MLP head. All f32.
// Sizes fixed by problem: N=50000, E=800000, F_IN=256, H=64, NG=64, NC=4.
//
// Graph structure: linked-list adjacency (2 chains per node) instead of CSR.
// Rationale (R3 counters): CSR fill's random 4B scatter caused 55 MB of
// write-amplified HBM traffic (16x); linked-list build writes only coalesced
// nxt[] + L2-resident head[]/cnt[] atomics.

#define TPB 256

// ---------------- build: degree count + 2-way linked chains ----------------

__global__ __launch_bounds__(TPB) void k_build(const int* __restrict__ dstv, int E,
                                               int* __restrict__ cnt,
                                               int* __restrict__ head,
                                               int* __restrict__ nxt) {
    int i = blockIdx.x * TPB + threadIdx.x;
    if (i < E) {
        int d = dstv[i];
        atomicAdd(&cnt[d], 1);
        int old = atomicExch(&head[d * 2 + (i & 1)], i + 1);  // 0 = end-of-chain
        nxt[i] = old;                                          // coalesced write
    }
}

// dinv[i] = rsqrt(cnt[i] + 1)  (self loop)
__global__ __launch_bounds__(TPB) void k_dinv(const int* __restrict__ cnt, int n,
                                              float* __restrict__ dinv) {
    int base = (blockIdx.x * TPB + threadIdx.x) * 4;
    if (base + 4 <= n) {
        int4 v = *(const int4*)(cnt + base);
        float4 dv;
        dv.x = rsqrtf((float)(v.x + 1));
        dv.y = rsqrtf((float)(v.y + 1));
        dv.z = rsqrtf((float)(v.z + 1));
        dv.w = rsqrtf((float)(v.w + 1));
        *(float4*)(dinv + base) = dv;
    } else {
        for (int i = base; i < n; i++) dinv[i] = rsqrtf((float)(cnt[i] + 1));
    }
}

// ---------------- GEMM: C[r][j] = dinv[r] * sum_k A[r][k] * W[k][j], j in [0,64) ----------------

template <int K>
__global__ __launch_bounds__(TPB) void k_gemm_scaled(const float* __restrict__ A,
                                                     const float* __restrict__ W,
                                                     const float* __restrict__ dinv,
                                                     float* __restrict__ C, int n) {
    __shared__ __align__(16) float Wc[64 * 64];
    __shared__ __align__(16) float xr[64 * 68];
    const int t = threadIdx.x;
    const int wave = t >> 6, lane = t & 63;
    const int li = lane >> 4, lj = lane & 15;
    const int rl0 = wave * 16 + li * 4;
    const int rbase = blockIdx.x * 64;

    float acc[4][4] = {{0.f,0.f,0.f,0.f},{0.f,0.f,0.f,0.f},{0.f,0.f,0.f,0.f},{0.f,0.f,0.f,0.f}};

    for (int kc = 0; kc < K; kc += 64) {
        {
            const float4* wsv = (const float4*)(W + (size_t)kc * 64);
            float4* wd = (float4*)Wc;
#pragma unroll
            for (int q = 0; q < 4; q++) wd[t + q * 256] = wsv[t + q * 256];
        }
        {
            int rl = t >> 2;
            int kq = (t & 3) * 16;
            int r = rbase + rl;
#pragma unroll
            for (int m = 0; m < 16; m += 4) {
                float4 xv;
                if (r < n) xv = *(const float4*)&A[(size_t)r * K + kc + kq + m];
                else       xv = make_float4(0.f, 0.f, 0.f, 0.f);
                *(float4*)&xr[rl * 68 + kq + m] = xv;
            }
        }
        __syncthreads();
#pragma unroll 8
        for (int kk = 0; kk < 64; kk++) {
            float4 wv = *(const float4*)&Wc[kk * 64 + lj * 4];
            float x0 = xr[(rl0 + 0) * 68 + kk];
            float x1 = xr[(rl0 + 1) * 68 + kk];
            float x2 = xr[(rl0 + 2) * 68 + kk];
            float x3 = xr[(rl0 + 3) * 68 + kk];
            acc[0][0] += x0 * wv.x; acc[0][1] += x0 * wv.y; acc[0][2] += x0 * wv.z; acc[0][3] += x0 * wv.w;
            acc[1][0] += x1 * wv.x; acc[1][1] += x1 * wv.y; acc[1][2] += x1 * wv.z; acc[1][3] += x1 * wv.w;
            acc[2][0] += x2 * wv.x; acc[2][1] += x2 * wv.y; acc[2][2] += x2 * wv.z; acc[2][3] += x2 * wv.w;
            acc[3][0] += x3 * wv.x; acc[3][1] += x3 * wv.y; acc[3][2] += x3 * wv.z; acc[3][3] += x3 * wv.w;
        }
        __syncthreads();
    }

#pragma unroll
    for (int ri = 0; ri < 4; ri++) {
        int r = rbase + rl0 + ri;
        if (r < n) {
            float d = dinv[r];
            float4 o = make_float4(acc[ri][0] * d, acc[ri][1] * d, acc[ri][2] * d, acc[ri][3] * d);
            *(float4*)&C[(size_t)r * 64 + lj * 4] = o;
        }
    }
}

// ---------------- Aggregation via chain walk ----------------
// out[i] = relu(dinv[i]*(sum_{src->i} hs[src] + hs[i]) + b)
// one wave per node; 64 lanes = 64 features; 2 concurrent chains.

__global__ __launch_bounds__(TPB) void k_agg(const float* __restrict__ hs,
                                             const int* __restrict__ head,
                                             const int* __restrict__ nxt,
                                             const int* __restrict__ srcv,
                                             const float* __restrict__ dinv,
                                             const float* __restrict__ bias,
                                             float* __restrict__ out, int n) {
    int node = blockIdx.x * 4 + (threadIdx.x >> 6);
    int lane = threadIdx.x & 63;
    if (node >= n) return;

    float acc = hs[(size_t)node * 64 + lane];  // self loop
    int hA = head[node * 2 + 0];
    int hB = head[node * 2 + 1];
    hA = __builtin_amdgcn_readfirstlane(hA);   // wave-uniform -> SALU/scalar loads
    hB = __builtin_amdgcn_readfirstlane(hB);

    while (hA | hB) {
        if (hA) {
            int k = hA - 1;
            int s = srcv[k];
            int nx = nxt[k];
            acc += hs[(size_t)s * 64 + lane];
            hA = __builtin_amdgcn_readfirstlane(nx);
        }
        if (hB) {
            int k = hB - 1;
            int s = srcv[k];
            int nx = nxt[k];
            acc += hs[(size_t)s * 64 + lane];
            hB = __builtin_amdgcn_readfirstlane(nx);
        }
    }
    float v = dinv[node] * acc + bias[lane];
    out[(size_t)node * 64 + lane] = fmaxf(v, 0.f);
}

// ---------------- Pool: sorted batch; uniform-chunk fast path ----------------

__global__ __launch_bounds__(TPB) void k_pool(const float* __restrict__ h,
                                              const int* __restrict__ batch, int n,
                                              float* __restrict__ gsum,
                                              int* __restrict__ gcnt) {
    const int CH = 16;
    int wid = blockIdx.x * 4 + (threadIdx.x >> 6);
    int lane = threadIdx.x & 63;
    int i0 = wid * CH;
    if (i0 >= n) return;
    int i1 = i0 + CH; if (i1 > n) i1 = n;
    int g0 = batch[i0];
    int g1 = batch[i1 - 1];
    if (g0 == g1) {
        float acc = 0.f;
#pragma unroll
        for (int i = 0; i < CH; i++) {
            int idx = i0 + i;
            if (idx < i1) acc += h[(size_t)idx * 64 + lane];
        }
        atomicAdd(&gsum[g0 * 64 + lane], acc);
        if (lane == 0) atomicAdd(&gcnt[g0], i1 - i0);
    } else {
        int cur = g0;
        float acc = 0.f;
        int cnt = 0;
        for (int i = i0; i < i1; i++) {
            int g = batch[i];
            if (g != cur) {
                atomicAdd(&gsum[cur * 64 + lane], acc);
                if (lane == 0) atomicAdd(&gcnt[cur], cnt);
                acc = 0.f; cnt = 0; cur = g;
            }
            acc += h[(size_t)i * 64 + lane];
            cnt++;
        }
        atomicAdd(&gsum[cur * 64 + lane], acc);
        if (lane == 0) atomicAdd(&gcnt[cur], cnt);
    }
}

// ---------------- Head ----------------

__global__ __launch_bounds__(TPB) void k_mlp(const float* __restrict__ gsum,
                                             const int* __restrict__ gcnt,
                                             const float* __restrict__ fc1w,
                                             const float* __restrict__ fc1b,
                                             const float* __restrict__ fc2w,
                                             const float* __restrict__ fc2b,
                                             float* __restrict__ out) {
    __shared__ float pooled[64 * 64];
    __shared__ float z[64 * 128];
    int t = threadIdx.x;
    for (int idx = t; idx < 64 * 64; idx += TPB) {
        int g = idx >> 6;
        int c = gcnt[g]; if (c < 1) c = 1;
        pooled[idx] = gsum[idx] / (float)c;
    }
    __syncthreads();
    for (int idx = t; idx < 64 * 128; idx += TPB) {
        int g = idx >> 7, o = idx & 127;
        float a = fc1b[o];
#pragma unroll 8
        for (int j = 0; j < 64; j++) a += pooled[g * 64 + j] * fc1w[j * 128 + o];
        z[idx] = fmaxf(a, 0.f);
    }
    __syncthreads();
    {
        int g = t >> 2, c = t & 3;
        float a = fc2b[c];
#pragma unroll 8
        for (int o = 0; o < 128; o++) a += z[g * 128 + o] * fc2w[o * 4 + c];
        out[t] = a;
    }
}

// ---------------- launch ----------------

extern "C" void kernel_launch(void* const* d_in, const int* in_sizes, int n_in,
                              void* d_out, int out_size, void* d_ws, size_t ws_size,
                              hipStream_t stream) {
    const float* x    = (const float*)d_in[0];
    const int*   ei   = (const int*)d_in[1];
    const int*   batch= (const int*)d_in[2];
    const float* W1   = (const float*)d_in[3];
    const float* b1   = (const float*)d_in[4];
    const float* W2   = (const float*)d_in[5];
    const float* b2   = (const float*)d_in[6];
    const float* fc1w = (const float*)d_in[7];
    const float* fc1b = (const float*)d_in[8];
    const float* fc2w = (const float*)d_in[9];
    const float* fc2b = (const float*)d_in[10];

    const int n = in_sizes[2];        // 50000
    const int E = in_sizes[1] / 2;    // 800000
    const int* srcv = ei;
    const int* dstv = ei + E;

    // workspace carve; zeroed region contiguous at front
    char* w = (char*)d_ws;
    int*   cnt    = (int*)w;            w += (size_t)n * 4;
    int*   head   = (int*)w;            w += (size_t)n * 2 * 4;
    int*   gcnt   = (int*)w;            w += 64 * 4;
    float* gsum   = (float*)w;          w += 64 * 64 * 4;
    size_t zbytes = (size_t)w - (size_t)d_ws;
    int*   nxt    = (int*)w;            w += (size_t)E * 4;
    float* dinv   = (float*)w;          w += (size_t)n * 4;
    w = (char*)(((size_t)w + 255) & ~(size_t)255);
    float* hs = (float*)w;              w += (size_t)n * 64 * 4;
    float* hb = (float*)w;              w += (size_t)n * 64 * 4;

    hipMemsetAsync(d_ws, 0, zbytes, stream);

    int gE = (E + TPB - 1) / TPB;
    k_build<<<gE, TPB, 0, stream>>>(dstv, E, cnt, head, nxt);
    k_dinv<<<(n + TPB * 4 - 1) / (TPB * 4), TPB, 0, stream>>>(cnt, n, dinv);

    int gRows = (n + 63) / 64;
    int gNode = (n + 3) / 4;
    k_gemm_scaled<256><<<gRows, TPB, 0, stream>>>(x, W1, dinv, hs, n);
    k_agg<<<gNode, TPB, 0, stream>>>(hs, head, nxt, srcv, dinv, b1, hb, n);
    k_gemm_scaled<64><<<gRows, TPB, 0, stream>>>(hb, W2, dinv, hs, n);
    k_agg<<<gNode, TPB, 0, stream>>>(hs, head, nxt, srcv, dinv, b2, hb, n);

    int nwaves16 = (n + 15) / 16;
    k_pool<<<(nwaves16 + 3) / 4, TPB, 0, stream>>>(hb, batch, n, gsum, gcnt);
    k_mlp<<<1, TPB, 0, stream>>>(gsum, gcnt, fc1w, fc1b, fc2w, fc2b, (float*)d_out);
}

// Round 5
// 378.010 us; speedup vs baseline: 1.1865x; 1.1865x over previous
//
#include <hip/hip_runtime.h>

// GNN: 2x GCNConv(relu) + mean-pool + MLP head. All f32.
// Sizes fixed by problem: N=50000, E=800000, F_IN=256, H=64, NG=64, NC=4.
//
// R4 lesson: linked-list adjacency amplified k_agg's reads (175 MB/dispatch,
// nxt/srcv random 64B lines per edge). CSR gather is right for the consumer;
// the build scatter is fixed instead via 2-pass bucketing (256 nodes/bucket,
// csr region per bucket is contiguous -> coalesced run writes).

#define TPB 256
#define SCAN_CHUNK 1024
#define CHUNK_A 16384   // edges per pass-A block

// ---------------- degree count ----------------

__global__ __launch_bounds__(TPB) void k_deg(const int* __restrict__ dstv, int E,
                                             int* __restrict__ cnt) {
    int i = blockIdx.x * TPB + threadIdx.x;
    if (i < E) atomicAdd(&cnt[dstv[i]], 1);
}

// ---- hierarchical exclusive scan of cnt -> csr_off (+ dinv, + per-bucket gcur) ----
__global__ __launch_bounds__(TPB) void k_scan1(const int* __restrict__ cnt, int n,
                                               int* __restrict__ bsum) {
    int t = threadIdx.x;
    int base = blockIdx.x * SCAN_CHUNK + t * 4;
    int s = 0;
    if (base + 4 <= n) {
        int4 v = *(const int4*)(cnt + base);
        s = v.x + v.y + v.z + v.w;
    } else {
        for (int i = base; i < n; i++) s += cnt[i];
    }
    __shared__ int r[TPB];
    r[t] = s;
    __syncthreads();
    for (int off = 128; off > 0; off >>= 1) {
        if (t < off) r[t] += r[t + off];
        __syncthreads();
    }
    if (t == 0) bsum[blockIdx.x] = r[0];
}

__global__ __launch_bounds__(TPB) void k_scan2(const int* __restrict__ bsum, int nb,
                                               int* __restrict__ boff,
                                               int* __restrict__ csr_off, int n) {
    __shared__ int r[TPB];
    int t = threadIdx.x;
    int v = (t < nb) ? bsum[t] : 0;
    r[t] = v;
    __syncthreads();
    for (int off = 1; off < TPB; off <<= 1) {
        int u = (t >= off) ? r[t - off] : 0;
        __syncthreads();
        r[t] += u;
        __syncthreads();
    }
    if (t < nb) boff[t] = r[t] - v;
    if (t == TPB - 1) csr_off[n] = r[TPB - 1];
}

__global__ __launch_bounds__(TPB) void k_scan3(const int* __restrict__ cnt, int n,
                                               const int* __restrict__ boff,
                                               int* __restrict__ csr_off,
                                               float* __restrict__ dinv,
                                               int* __restrict__ gcur) {
    int t = threadIdx.x;
    int base = blockIdx.x * SCAN_CHUNK + t * 4;
    int4 v = make_int4(0, 0, 0, 0);
    bool full = (base + 4 <= n);
    if (full) {
        v = *(const int4*)(cnt + base);
    } else {
        int tmp[4] = {0, 0, 0, 0};
        for (int i = 0; i < 4; i++) if (base + i < n) tmp[i] = cnt[base + i];
        v = make_int4(tmp[0], tmp[1], tmp[2], tmp[3]);
    }
    int s = v.x + v.y + v.z + v.w;
    __shared__ int r[TPB];
    r[t] = s;
    __syncthreads();
    for (int off = 1; off < TPB; off <<= 1) {
        int u = (t >= off) ? r[t - off] : 0;
        __syncthreads();
        r[t] += u;
        __syncthreads();
    }
    int run = boff[blockIdx.x] + r[t] - s;
    if (full) {
        int4 o;
        o.x = run;
        o.y = run + v.x;
        o.z = o.y + v.y;
        o.w = o.z + v.z;
        *(int4*)(csr_off + base) = o;
        if ((base & 255) == 0) gcur[base >> 8] = o.x;   // bucket cursor init
        float4 dv;
        dv.x = rsqrtf((float)(v.x + 1));
        dv.y = rsqrtf((float)(v.y + 1));
        dv.z = rsqrtf((float)(v.z + 1));
        dv.w = rsqrtf((float)(v.w + 1));
        *(float4*)(dinv + base) = dv;
    } else {
        int e[4] = {v.x, v.y, v.z, v.w};
        for (int i = 0; i < 4; i++) {
            int idx = base + i;
            if (idx < n) {
                csr_off[idx] = run;
                if ((idx & 255) == 0) gcur[idx >> 8] = run;
                dinv[idx] = rsqrtf((float)(e[i] + 1));
                run += e[i];
            }
        }
    }
}

// ---------------- pass A: bucket edges (256 nodes/bucket) into csr regions ----------------
// writes packed (src<<8 | dst&255) in per-bucket runs; near-1x write amplification.
// requires n <= 65536 (src fits 16 bits -> packed fits 24 bits) and nbuck <= 256.

__global__ __launch_bounds__(TPB) void k_passA(const int* __restrict__ srcv,
                                               const int* __restrict__ dstv, int E,
                                               int* __restrict__ gcur,
                                               int* __restrict__ csr_src, int nbuck) {
    __shared__ int pk[CHUNK_A];     // 64 KB packed staging, bucket-ordered
    __shared__ int hist[256];
    __shared__ int ebase[256];      // exclusive scan of hist
    __shared__ int gbase[256];      // global run base
    __shared__ int lcur[256];
    int t = threadIdx.x;
    int e0 = blockIdx.x * CHUNK_A;
    int e1 = e0 + CHUNK_A; if (e1 > E) e1 = E;

    hist[t] = 0; lcur[t] = 0;
    __syncthreads();
    for (int i = e0 + t; i < e1; i += TPB) atomicAdd(&hist[dstv[i] >> 8], 1);
    __syncthreads();
    // exclusive scan of hist (256 entries, Hillis-Steele)
    int v = hist[t];
    ebase[t] = v;
    __syncthreads();
    for (int off = 1; off < 256; off <<= 1) {
        int u = (t >= off) ? ebase[t - off] : 0;
        __syncthreads();
        ebase[t] += u;
        __syncthreads();
    }
    ebase[t] -= v;                  // now exclusive (each thread owns entry t)
    if (t < nbuck && v > 0) gbase[t] = atomicAdd(&gcur[t], v);
    __syncthreads();
    // scatter into LDS bucket-ordered
    for (int i = e0 + t; i < e1; i += TPB) {
        int d = dstv[i];
        int s = srcv[i];
        int b = d >> 8;
        int r = atomicAdd(&lcur[b], 1);
        pk[ebase[b] + r] = (s << 8) | (d & 255);
    }
    __syncthreads();
    // copy runs out (wave per bucket round-robin; runs avg ~84 words, contiguous)
    int wave = t >> 6, lane = t & 63;
    for (int b = wave; b < nbuck; b += 4) {
        int c = hist[b];
        int lb = ebase[b];
        int gb = gbase[b];
        for (int j = lane; j < c; j += 64) csr_src[gb + j] = pk[lb + j];
    }
}

// ---------------- pass B: per-bucket in-place sort to per-node order ----------------
// node base comes straight from csr_off; writes confined to this block's region.

__global__ __launch_bounds__(TPB) void k_passB(int* __restrict__ csr_src,
                                               const int* __restrict__ csr_off, int n) {
    __shared__ int pk[8192];        // bucket edges (mean 4096, 64-sigma safe)
    __shared__ int nbase[256];
    __shared__ int cur[256];
    int b = blockIdx.x;
    int n0 = b << 8;
    int n1 = n0 + 256; if (n1 > n) n1 = n;
    int s0 = csr_off[n0];
    int s1 = csr_off[n1];
    int cnt = s1 - s0;
    int t = threadIdx.x;
    nbase[t] = (n0 + t < n1) ? (csr_off[n0 + t] - s0) : cnt;
    cur[t] = 0;
    for (int i = t; i < cnt; i += TPB) pk[i] = csr_src[s0 + i];
    __syncthreads();
    for (int i = t; i < cnt; i += TPB) {
        int p = pk[i];
        int dloc = p & 255;
        int r = atomicAdd(&cur[dloc], 1);
        csr_src[s0 + nbase[dloc] + r] = p >> 8;
    }
}

// ---------------- GEMM: C[r][j] = dinv[r] * sum_k A[r][k] * W[k][j], j in [0,64) ----------------

template <int K>
__global__ __launch_bounds__(TPB) void k_gemm_scaled(const float* __restrict__ A,
                                                     const float* __restrict__ W,
                                                     const float* __restrict__ dinv,
                                                     float* __restrict__ C, int n) {
    __shared__ __align__(16) float Wc[64 * 64];
    __shared__ __align__(16) float xr[64 * 68];
    const int t = threadIdx.x;
    const int wave = t >> 6, lane = t & 63;
    const int li = lane >> 4, lj = lane & 15;
    const int rl0 = wave * 16 + li * 4;
    const int rbase = blockIdx.x * 64;

    float acc[4][4] = {{0.f,0.f,0.f,0.f},{0.f,0.f,0.f,0.f},{0.f,0.f,0.f,0.f},{0.f,0.f,0.f,0.f}};

    for (int kc = 0; kc < K; kc += 64) {
        {
            const float4* wsv = (const float4*)(W + (size_t)kc * 64);
            float4* wd = (float4*)Wc;
#pragma unroll
            for (int q = 0; q < 4; q++) wd[t + q * 256] = wsv[t + q * 256];
        }
        {
            int rl = t >> 2;
            int kq = (t & 3) * 16;
            int r = rbase + rl;
#pragma unroll
            for (int m = 0; m < 16; m += 4) {
                float4 xv;
                if (r < n) xv = *(const float4*)&A[(size_t)r * K + kc + kq + m];
                else       xv = make_float4(0.f, 0.f, 0.f, 0.f);
                *(float4*)&xr[rl * 68 + kq + m] = xv;
            }
        }
        __syncthreads();
#pragma unroll 8
        for (int kk = 0; kk < 64; kk++) {
            float4 wv = *(const float4*)&Wc[kk * 64 + lj * 4];
            float x0 = xr[(rl0 + 0) * 68 + kk];
            float x1 = xr[(rl0 + 1) * 68 + kk];
            float x2 = xr[(rl0 + 2) * 68 + kk];
            float x3 = xr[(rl0 + 3) * 68 + kk];
            acc[0][0] += x0 * wv.x; acc[0][1] += x0 * wv.y; acc[0][2] += x0 * wv.z; acc[0][3] += x0 * wv.w;
            acc[1][0] += x1 * wv.x; acc[1][1] += x1 * wv.y; acc[1][2] += x1 * wv.z; acc[1][3] += x1 * wv.w;
            acc[2][0] += x2 * wv.x; acc[2][1] += x2 * wv.y; acc[2][2] += x2 * wv.z; acc[2][3] += x2 * wv.w;
            acc[3][0] += x3 * wv.x; acc[3][1] += x3 * wv.y; acc[3][2] += x3 * wv.z; acc[3][3] += x3 * wv.w;
        }
        __syncthreads();
    }

#pragma unroll
    for (int ri = 0; ri < 4; ri++) {
        int r = rbase + rl0 + ri;
        if (r < n) {
            float d = dinv[r];
            float4 o = make_float4(acc[ri][0] * d, acc[ri][1] * d, acc[ri][2] * d, acc[ri][3] * d);
            *(float4*)&C[(size_t)r * 64 + lj * 4] = o;
        }
    }
}

// ---------------- Aggregation (CSR gather) ----------------

__global__ __launch_bounds__(TPB) void k_agg(const float* __restrict__ hs,
                                             const int* __restrict__ csr_off,
                                             const int* __restrict__ csr_src,
                                             const float* __restrict__ dinv,
                                             const float* __restrict__ bias,
                                             float* __restrict__ out, int n) {
    int node = blockIdx.x * 4 + (threadIdx.x >> 6);
    int lane = threadIdx.x & 63;
    if (node >= n) return;
    int p0 = csr_off[node];
    int p1 = csr_off[node + 1];
    float acc = hs[(size_t)node * 64 + lane];  // self loop
    int p = p0;
    for (; p + 4 <= p1; p += 4) {
        int s0 = csr_src[p + 0];
        int s1 = csr_src[p + 1];
        int s2 = csr_src[p + 2];
        int s3 = csr_src[p + 3];
        float a0 = hs[(size_t)s0 * 64 + lane];
        float a1 = hs[(size_t)s1 * 64 + lane];
        float a2 = hs[(size_t)s2 * 64 + lane];
        float a3 = hs[(size_t)s3 * 64 + lane];
        acc += (a0 + a1) + (a2 + a3);
    }
    for (; p < p1; p++) acc += hs[(size_t)csr_src[p] * 64 + lane];
    float v = dinv[node] * acc + bias[lane];
    out[(size_t)node * 64 + lane] = fmaxf(v, 0.f);
}

// ---------------- Pool: sorted batch; uniform-chunk fast path ----------------

__global__ __launch_bounds__(TPB) void k_pool(const float* __restrict__ h,
                                              const int* __restrict__ batch, int n,
                                              float* __restrict__ gsum,
                                              int* __restrict__ gcnt) {
    const int CH = 16;
    int wid = blockIdx.x * 4 + (threadIdx.x >> 6);
    int lane = threadIdx.x & 63;
    int i0 = wid * CH;
    if (i0 >= n) return;
    int i1 = i0 + CH; if (i1 > n) i1 = n;
    int g0 = batch[i0];
    int g1 = batch[i1 - 1];
    if (g0 == g1) {
        float acc = 0.f;
#pragma unroll
        for (int i = 0; i < CH; i++) {
            int idx = i0 + i;
            if (idx < i1) acc += h[(size_t)idx * 64 + lane];
        }
        atomicAdd(&gsum[g0 * 64 + lane], acc);
        if (lane == 0) atomicAdd(&gcnt[g0], i1 - i0);
    } else {
        int cur = g0;
        float acc = 0.f;
        int cnt = 0;
        for (int i = i0; i < i1; i++) {
            int g = batch[i];
            if (g != cur) {
                atomicAdd(&gsum[cur * 64 + lane], acc);
                if (lane == 0) atomicAdd(&gcnt[cur], cnt);
                acc = 0.f; cnt = 0; cur = g;
            }
            acc += h[(size_t)i * 64 + lane];
            cnt++;
        }
        atomicAdd(&gsum[cur * 64 + lane], acc);
        if (lane == 0) atomicAdd(&gcnt[cur], cnt);
    }
}

// ---------------- Head ----------------

__global__ __launch_bounds__(TPB) void k_mlp(const float* __restrict__ gsum,
                                             const int* __restrict__ gcnt,
                                             const float* __restrict__ fc1w,
                                             const float* __restrict__ fc1b,
                                             const float* __restrict__ fc2w,
                                             const float* __restrict__ fc2b,
                                             float* __restrict__ out) {
    __shared__ float pooled[64 * 64];
    __shared__ float z[64 * 128];
    int t = threadIdx.x;
    for (int idx = t; idx < 64 * 64; idx += TPB) {
        int g = idx >> 6;
        int c = gcnt[g]; if (c < 1) c = 1;
        pooled[idx] = gsum[idx] / (float)c;
    }
    __syncthreads();
    for (int idx = t; idx < 64 * 128; idx += TPB) {
        int g = idx >> 7, o = idx & 127;
        float a = fc1b[o];
#pragma unroll 8
        for (int j = 0; j < 64; j++) a += pooled[g * 64 + j] * fc1w[j * 128 + o];
        z[idx] = fmaxf(a, 0.f);
    }
    __syncthreads();
    {
        int g = t >> 2, c = t & 3;
        float a = fc2b[c];
#pragma unroll 8
        for (int o = 0; o < 128; o++) a += z[g * 128 + o] * fc2w[o * 4 + c];
        out[t] = a;
    }
}

// ---------------- launch ----------------

extern "C" void kernel_launch(void* const* d_in, const int* in_sizes, int n_in,
                              void* d_out, int out_size, void* d_ws, size_t ws_size,
                              hipStream_t stream) {
    const float* x    = (const float*)d_in[0];
    const int*   ei   = (const int*)d_in[1];
    const int*   batch= (const int*)d_in[2];
    const float* W1   = (const float*)d_in[3];
    const float* b1   = (const float*)d_in[4];
    const float* W2   = (const float*)d_in[5];
    const float* b2   = (const float*)d_in[6];
    const float* fc1w = (const float*)d_in[7];
    const float* fc1b = (const float*)d_in[8];
    const float* fc2w = (const float*)d_in[9];
    const float* fc2b = (const float*)d_in[10];

    const int n = in_sizes[2];        // 50000
    const int E = in_sizes[1] / 2;    // 800000
    const int* srcv = ei;
    const int* dstv = ei + E;

    // workspace carve; zeroed region contiguous at front
    char* w = (char*)d_ws;
    int*   cnt    = (int*)w;            w += (size_t)n * 4;
    int*   gcnt   = (int*)w;            w += 64 * 4;
    float* gsum   = (float*)w;          w += 64 * 64 * 4;
    size_t zbytes = (size_t)w - (size_t)d_ws;
    int*   csr_off= (int*)w;            w += (size_t)(n + 1) * 4;
    float* dinv   = (float*)w;          w += (size_t)n * 4;
    int*   csr_src= (int*)w;            w += (size_t)E * 4;
    int*   gcur   = (int*)w;            w += 256 * 4;
    int*   bsum   = (int*)w;            w += 256 * 4;
    int*   boff   = (int*)w;            w += 256 * 4;
    w = (char*)(((size_t)w + 255) & ~(size_t)255);
    float* hs = (float*)w;              w += (size_t)n * 64 * 4;
    float* hb = (float*)w;              w += (size_t)n * 64 * 4;

    hipMemsetAsync(d_ws, 0, zbytes, stream);

    int gE = (E + TPB - 1) / TPB;
    k_deg<<<gE, TPB, 0, stream>>>(dstv, E, cnt);

    int nb = (n + SCAN_CHUNK - 1) / SCAN_CHUNK;   // 49
    k_scan1<<<nb, TPB, 0, stream>>>(cnt, n, bsum);
    k_scan2<<<1, TPB, 0, stream>>>(bsum, nb, boff, csr_off, n);
    k_scan3<<<nb, TPB, 0, stream>>>(cnt, n, boff, csr_off, dinv, gcur);

    int nbuck = (n + 255) >> 8;                   // 196 (<=256 required)
    int gA = (E + CHUNK_A - 1) / CHUNK_A;         // 49
    k_passA<<<gA, TPB, 0, stream>>>(srcv, dstv, E, gcur, csr_src, nbuck);
    k_passB<<<nbuck, TPB, 0, stream>>>(csr_src, csr_off, n);

    int gRows = (n + 63) / 64;
    int gNode = (n + 3) / 4;
    k_gemm_scaled<256><<<gRows, TPB, 0, stream>>>(x, W1, dinv, hs, n);
    k_agg<<<gNode, TPB, 0, stream>>>(hs, csr_off, csr_src, dinv, b1, hb, n);
    k_gemm_scaled<64><<<gRows, TPB, 0, stream>>>(hb, W2, dinv, hs, n);
    k_agg<<<gNode, TPB, 0, stream>>>(hs, csr_off, csr_src, dinv, b2, hb, n);

    int nwaves16 = (n + 15) / 16;
    k_pool<<<(nwaves16 + 3) / 4, TPB, 0, stream>>>(hb, batch, n, gsum, gcnt);
    k_mlp<<<1, TPB, 0, stream>>>(gsum, gcnt, fc1w, fc1b, fc2w, fc2b, (float*)d_out);
}

// Round 6
// 316.841 us; speedup vs baseline: 1.4155x; 1.1931x over previous
//
#include <hip/hip_runtime.h>

// GNN: 2x GCNConv(relu) + mean-pool + MLP head. All f32.
// Sizes fixed by problem: N=50000, E=800000, F_IN=256, H=64, NG=64, NC=4.
//
// Build pipeline (R5 lesson: parallelism > chunk size):
//   passA (196 blocks, 4096 edges each): LDS bucket-histogram + bucket-ordered
//          staging, runs copied to per-bucket slack regions (cap=4608).
//   boff  (1 block): 196-entry scan of bucket totals.
//   passB (196 blocks): per-node hist+scan in LDS -> csr_off, dinv, sorted csr_src.
// No node-level global scan, no k_deg: passA cursors ARE the bucket totals.

#define TPB 256
#define CHUNK_A 4096
#define BCAP 4608          // per-bucket staging capacity (mean 4096, +8 sigma)

// ---------------- pass A: chunked bucket staging ----------------
// packed edge: (src<<8) | (dst & 255); requires n <= 65536, nbuck <= 256.

__global__ __launch_bounds__(TPB) void k_passA(const int* __restrict__ srcv,
                                               const int* __restrict__ dstv, int E,
                                               int* __restrict__ gcur,
                                               int* __restrict__ staged, int nbuck) {
    __shared__ int pk[CHUNK_A];     // 16 KB packed staging, bucket-ordered
    __shared__ int hist[256];
    __shared__ int ebase[256];
    __shared__ int gbase[256];
    __shared__ int lcur[256];
    int t = threadIdx.x;
    int e0 = blockIdx.x * CHUNK_A;
    int e1 = e0 + CHUNK_A; if (e1 > E) e1 = E;

    hist[t] = 0; lcur[t] = 0;
    __syncthreads();
    for (int i = e0 + t; i < e1; i += TPB) atomicAdd(&hist[dstv[i] >> 8], 1);
    __syncthreads();
    int v = hist[t];
    ebase[t] = v;
    __syncthreads();
    for (int off = 1; off < 256; off <<= 1) {
        int u = (t >= off) ? ebase[t - off] : 0;
        __syncthreads();
        ebase[t] += u;
        __syncthreads();
    }
    ebase[t] -= v;                  // exclusive
    if (t < nbuck && v > 0) gbase[t] = t * BCAP + atomicAdd(&gcur[t], v);
    __syncthreads();
    for (int i = e0 + t; i < e1; i += TPB) {
        int d = dstv[i];
        int s = srcv[i];
        int b = d >> 8;
        int r = atomicAdd(&lcur[b], 1);
        pk[ebase[b] + r] = (s << 8) | (d & 255);
    }
    __syncthreads();
    int wave = t >> 6, lane = t & 63;
    for (int b = wave; b < nbuck; b += 4) {
        int c = hist[b];
        int lb = ebase[b];
        int gb = gbase[b];
        for (int j = lane; j < c; j += 64) staged[gb + j] = pk[lb + j];
    }
}

// ---------------- bucket-offset scan (nbuck <= 256) ----------------

__global__ __launch_bounds__(TPB) void k_boff(const int* __restrict__ gcur, int nbuck,
                                              int* __restrict__ bucket_off) {
    __shared__ int r[TPB];
    int t = threadIdx.x;
    int v = (t < nbuck) ? gcur[t] : 0;
    r[t] = v;
    __syncthreads();
    for (int off = 1; off < TPB; off <<= 1) {
        int u = (t >= off) ? r[t - off] : 0;
        __syncthreads();
        r[t] += u;
        __syncthreads();
    }
    if (t < nbuck) bucket_off[t] = r[t] - v;
}

// ---------------- pass B: per-bucket node sort + csr_off + dinv ----------------

__global__ __launch_bounds__(TPB) void k_passB(const int* __restrict__ staged,
                                               const int* __restrict__ gcur,
                                               const int* __restrict__ bucket_off,
                                               int* __restrict__ csr_off,
                                               int* __restrict__ csr_src,
                                               float* __restrict__ dinv,
                                               int n, int nbuck) {
    __shared__ int pk[BCAP];        // 18 KB
    __shared__ int hist[256];
    __shared__ int nbase[256];
    __shared__ int cur[256];
    int b = blockIdx.x;
    int n0 = b << 8;
    int n1 = n0 + 256; if (n1 > n) n1 = n;
    int cnt = gcur[b];
    int base = bucket_off[b];
    int t = threadIdx.x;

    hist[t] = 0; cur[t] = 0;
    for (int i = t; i < cnt; i += TPB) pk[i] = staged[b * BCAP + i];
    __syncthreads();
    for (int i = t; i < cnt; i += TPB) atomicAdd(&hist[pk[i] & 255], 1);
    __syncthreads();
    int v = hist[t];
    nbase[t] = v;
    __syncthreads();
    for (int off = 1; off < 256; off <<= 1) {
        int u = (t >= off) ? nbase[t - off] : 0;
        __syncthreads();
        nbase[t] += u;
        __syncthreads();
    }
    nbase[t] -= v;                  // exclusive within bucket
    if (n0 + t < n1) {
        csr_off[n0 + t] = base + nbase[t];
        dinv[n0 + t] = rsqrtf((float)(v + 1));   // +1 self loop
    }
    if (b == nbuck - 1 && t == 0) csr_off[n] = base + cnt;
    __syncthreads();
    for (int i = t; i < cnt; i += TPB) {
        int p = pk[i];
        int dloc = p & 255;
        int r = atomicAdd(&cur[dloc], 1);
        csr_src[base + nbase[dloc] + r] = p >> 8;
    }
}

// ---------------- GEMM: C[r][j] = dinv[r] * sum_k A[r][k] * W[k][j], j in [0,64) ----------------

template <int K>
__global__ __launch_bounds__(TPB) void k_gemm_scaled(const float* __restrict__ A,
                                                     const float* __restrict__ W,
                                                     const float* __restrict__ dinv,
                                                     float* __restrict__ C, int n) {
    __shared__ __align__(16) float Wc[64 * 64];
    __shared__ __align__(16) float xr[64 * 68];
    const int t = threadIdx.x;
    const int wave = t >> 6, lane = t & 63;
    const int li = lane >> 4, lj = lane & 15;
    const int rl0 = wave * 16 + li * 4;
    const int rbase = blockIdx.x * 64;

    float acc[4][4] = {{0.f,0.f,0.f,0.f},{0.f,0.f,0.f,0.f},{0.f,0.f,0.f,0.f},{0.f,0.f,0.f,0.f}};

    for (int kc = 0; kc < K; kc += 64) {
        {
            const float4* wsv = (const float4*)(W + (size_t)kc * 64);
            float4* wd = (float4*)Wc;
#pragma unroll
            for (int q = 0; q < 4; q++) wd[t + q * 256] = wsv[t + q * 256];
        }
        {
            int rl = t >> 2;
            int kq = (t & 3) * 16;
            int r = rbase + rl;
#pragma unroll
            for (int m = 0; m < 16; m += 4) {
                float4 xv;
                if (r < n) xv = *(const float4*)&A[(size_t)r * K + kc + kq + m];
                else       xv = make_float4(0.f, 0.f, 0.f, 0.f);
                *(float4*)&xr[rl * 68 + kq + m] = xv;
            }
        }
        __syncthreads();
#pragma unroll 8
        for (int kk = 0; kk < 64; kk++) {
            float4 wv = *(const float4*)&Wc[kk * 64 + lj * 4];
            float x0 = xr[(rl0 + 0) * 68 + kk];
            float x1 = xr[(rl0 + 1) * 68 + kk];
            float x2 = xr[(rl0 + 2) * 68 + kk];
            float x3 = xr[(rl0 + 3) * 68 + kk];
            acc[0][0] += x0 * wv.x; acc[0][1] += x0 * wv.y; acc[0][2] += x0 * wv.z; acc[0][3] += x0 * wv.w;
            acc[1][0] += x1 * wv.x; acc[1][1] += x1 * wv.y; acc[1][2] += x1 * wv.z; acc[1][3] += x1 * wv.w;
            acc[2][0] += x2 * wv.x; acc[2][1] += x2 * wv.y; acc[2][2] += x2 * wv.z; acc[2][3] += x2 * wv.w;
            acc[3][0] += x3 * wv.x; acc[3][1] += x3 * wv.y; acc[3][2] += x3 * wv.z; acc[3][3] += x3 * wv.w;
        }
        __syncthreads();
    }

#pragma unroll
    for (int ri = 0; ri < 4; ri++) {
        int r = rbase + rl0 + ri;
        if (r < n) {
            float d = dinv[r];
            float4 o = make_float4(acc[ri][0] * d, acc[ri][1] * d, acc[ri][2] * d, acc[ri][3] * d);
            *(float4*)&C[(size_t)r * 64 + lj * 4] = o;
        }
    }
}

// ---------------- Aggregation (CSR gather), 8 rows in flight ----------------

__global__ __launch_bounds__(TPB) void k_agg(const float* __restrict__ hs,
                                             const int* __restrict__ csr_off,
                                             const int* __restrict__ csr_src,
                                             const float* __restrict__ dinv,
                                             const float* __restrict__ bias,
                                             float* __restrict__ out, int n) {
    int node = blockIdx.x * 4 + (threadIdx.x >> 6);
    int lane = threadIdx.x & 63;
    if (node >= n) return;
    int p0 = csr_off[node];
    int p1 = csr_off[node + 1];
    float acc = hs[(size_t)node * 64 + lane];  // self loop
    int p = p0;
    for (; p + 8 <= p1; p += 8) {
        int s0 = csr_src[p + 0];
        int s1 = csr_src[p + 1];
        int s2 = csr_src[p + 2];
        int s3 = csr_src[p + 3];
        int s4 = csr_src[p + 4];
        int s5 = csr_src[p + 5];
        int s6 = csr_src[p + 6];
        int s7 = csr_src[p + 7];
        float a0 = hs[(size_t)s0 * 64 + lane];
        float a1 = hs[(size_t)s1 * 64 + lane];
        float a2 = hs[(size_t)s2 * 64 + lane];
        float a3 = hs[(size_t)s3 * 64 + lane];
        float a4 = hs[(size_t)s4 * 64 + lane];
        float a5 = hs[(size_t)s5 * 64 + lane];
        float a6 = hs[(size_t)s6 * 64 + lane];
        float a7 = hs[(size_t)s7 * 64 + lane];
        acc += ((a0 + a1) + (a2 + a3)) + ((a4 + a5) + (a6 + a7));
    }
    for (; p < p1; p++) acc += hs[(size_t)csr_src[p] * 64 + lane];
    float v = dinv[node] * acc + bias[lane];
    out[(size_t)node * 64 + lane] = fmaxf(v, 0.f);
}

// ---------------- Pool: sorted batch; uniform-chunk fast path ----------------

__global__ __launch_bounds__(TPB) void k_pool(const float* __restrict__ h,
                                              const int* __restrict__ batch, int n,
                                              float* __restrict__ gsum,
                                              int* __restrict__ gcnt) {
    const int CH = 16;
    int wid = blockIdx.x * 4 + (threadIdx.x >> 6);
    int lane = threadIdx.x & 63;
    int i0 = wid * CH;
    if (i0 >= n) return;
    int i1 = i0 + CH; if (i1 > n) i1 = n;
    int g0 = batch[i0];
    int g1 = batch[i1 - 1];
    if (g0 == g1) {
        float acc = 0.f;
#pragma unroll
        for (int i = 0; i < CH; i++) {
            int idx = i0 + i;
            if (idx < i1) acc += h[(size_t)idx * 64 + lane];
        }
        atomicAdd(&gsum[g0 * 64 + lane], acc);
        if (lane == 0) atomicAdd(&gcnt[g0], i1 - i0);
    } else {
        int cur = g0;
        float acc = 0.f;
        int cnt = 0;
        for (int i = i0; i < i1; i++) {
            int g = batch[i];
            if (g != cur) {
                atomicAdd(&gsum[cur * 64 + lane], acc);
                if (lane == 0) atomicAdd(&gcnt[cur], cnt);
                acc = 0.f; cnt = 0; cur = g;
            }
            acc += h[(size_t)i * 64 + lane];
            cnt++;
        }
        atomicAdd(&gsum[cur * 64 + lane], acc);
        if (lane == 0) atomicAdd(&gcnt[cur], cnt);
    }
}

// ---------------- Head ----------------

__global__ __launch_bounds__(TPB) void k_mlp(const float* __restrict__ gsum,
                                             const int* __restrict__ gcnt,
                                             const float* __restrict__ fc1w,
                                             const float* __restrict__ fc1b,
                                             const float* __restrict__ fc2w,
                                             const float* __restrict__ fc2b,
                                             float* __restrict__ out) {
    __shared__ float pooled[64 * 64];
    __shared__ float z[64 * 128];
    int t = threadIdx.x;
    for (int idx = t; idx < 64 * 64; idx += TPB) {
        int g = idx >> 6;
        int c = gcnt[g]; if (c < 1) c = 1;
        pooled[idx] = gsum[idx] / (float)c;
    }
    __syncthreads();
    for (int idx = t; idx < 64 * 128; idx += TPB) {
        int g = idx >> 7, o = idx & 127;
        float a = fc1b[o];
#pragma unroll 8
        for (int j = 0; j < 64; j++) a += pooled[g * 64 + j] * fc1w[j * 128 + o];
        z[idx] = fmaxf(a, 0.f);
    }
    __syncthreads();
    {
        int g = t >> 2, c = t & 3;
        float a = fc2b[c];
#pragma unroll 8
        for (int o = 0; o < 128; o++) a += z[g * 128 + o] * fc2w[o * 4 + c];
        out[t] = a;
    }
}

// ---------------- launch ----------------

extern "C" void kernel_launch(void* const* d_in, const int* in_sizes, int n_in,
                              void* d_out, int out_size, void* d_ws, size_t ws_size,
                              hipStream_t stream) {
    const float* x    = (const float*)d_in[0];
    const int*   ei   = (const int*)d_in[1];
    const int*   batch= (const int*)d_in[2];
    const float* W1   = (const float*)d_in[3];
    const float* b1   = (const float*)d_in[4];
    const float* W2   = (const float*)d_in[5];
    const float* b2   = (const float*)d_in[6];
    const float* fc1w = (const float*)d_in[7];
    const float* fc1b = (const float*)d_in[8];
    const float* fc2w = (const float*)d_in[9];
    const float* fc2b = (const float*)d_in[10];

    const int n = in_sizes[2];        // 50000
    const int E = in_sizes[1] / 2;    // 800000
    const int* srcv = ei;
    const int* dstv = ei + E;
    const int nbuck = (n + 255) >> 8; // 196 (must be <= 256)

    // workspace carve; zeroed region contiguous at front
    char* w = (char*)d_ws;
    int*   gcur   = (int*)w;            w += 256 * 4;
    int*   gcnt   = (int*)w;            w += 64 * 4;
    float* gsum   = (float*)w;          w += 64 * 64 * 4;
    size_t zbytes = (size_t)w - (size_t)d_ws;
    int*   bucket_off = (int*)w;        w += 256 * 4;
    int*   csr_off= (int*)w;            w += (size_t)(n + 1) * 4;
    float* dinv   = (float*)w;          w += (size_t)n * 4;
    int*   csr_src= (int*)w;            w += (size_t)E * 4;
    int*   staged = (int*)w;            w += (size_t)nbuck * BCAP * 4;
    w = (char*)(((size_t)w + 255) & ~(size_t)255);
    float* hs = (float*)w;              w += (size_t)n * 64 * 4;
    float* hb = (float*)w;              w += (size_t)n * 64 * 4;

    hipMemsetAsync(d_ws, 0, zbytes, stream);

    int gA = (E + CHUNK_A - 1) / CHUNK_A;   // 196
    k_passA<<<gA, TPB, 0, stream>>>(srcv, dstv, E, gcur, staged, nbuck);
    k_boff<<<1, TPB, 0, stream>>>(gcur, nbuck, bucket_off);
    k_passB<<<nbuck, TPB, 0, stream>>>(staged, gcur, bucket_off, csr_off, csr_src,
                                       dinv, n, nbuck);

    int gRows = (n + 63) / 64;
    int gNode = (n + 3) / 4;
    k_gemm_scaled<256><<<gRows, TPB, 0, stream>>>(x, W1, dinv, hs, n);
    k_agg<<<gNode, TPB, 0, stream>>>(hs, csr_off, csr_src, dinv, b1, hb, n);
    k_gemm_scaled<64><<<gRows, TPB, 0, stream>>>(hb, W2, dinv, hs, n);
    k_agg<<<gNode, TPB, 0, stream>>>(hs, csr_off, csr_src, dinv, b2, hb, n);

    int nwaves16 = (n + 15) / 16;
    k_pool<<<(nwaves16 + 3) / 4, TPB, 0, stream>>>(hb, batch, n, gsum, gcnt);
    k_mlp<<<1, TPB, 0, stream>>>(gsum, gcnt, fc1w, fc1b, fc2w, fc2b, (float*)d_out);
}

// Round 7
// 281.690 us; speedup vs baseline: 1.5922x; 1.1248x over previous
//
#include <hip/hip_runtime.h>

// GNN: 2x GCNConv(relu) + mean-pool + MLP head. All f32.
// Sizes fixed by problem: N=50000, E=800000, F_IN=256, H=64, NG=64, NC=4.
//
// Build pipeline: passA (196 blocks) bucket staging -> boff scan -> passB
// per-bucket node sort. Head split across blocks (R6 lesson: single-block
// latency-bound kernels cost ~45us regardless of work).

#define TPB 256
#define CHUNK_A 4096
#define BCAP 4608          // per-bucket staging capacity (mean 4096, +8 sigma)

// ---------------- pass A: chunked bucket staging ----------------
// packed edge: (src<<8) | (dst & 255); requires n <= 65536, nbuck <= 256.

__global__ __launch_bounds__(TPB) void k_passA(const int* __restrict__ srcv,
                                               const int* __restrict__ dstv, int E,
                                               int* __restrict__ gcur,
                                               int* __restrict__ staged, int nbuck) {
    __shared__ int pk[CHUNK_A];
    __shared__ int hist[256];
    __shared__ int ebase[256];
    __shared__ int gbase[256];
    __shared__ int lcur[256];
    int t = threadIdx.x;
    int e0 = blockIdx.x * CHUNK_A;
    int e1 = e0 + CHUNK_A; if (e1 > E) e1 = E;

    hist[t] = 0; lcur[t] = 0;
    __syncthreads();
    for (int i = e0 + t; i < e1; i += TPB) atomicAdd(&hist[dstv[i] >> 8], 1);
    __syncthreads();
    int v = hist[t];
    ebase[t] = v;
    __syncthreads();
    for (int off = 1; off < 256; off <<= 1) {
        int u = (t >= off) ? ebase[t - off] : 0;
        __syncthreads();
        ebase[t] += u;
        __syncthreads();
    }
    ebase[t] -= v;
    if (t < nbuck && v > 0) gbase[t] = t * BCAP + atomicAdd(&gcur[t], v);
    __syncthreads();
    for (int i = e0 + t; i < e1; i += TPB) {
        int d = dstv[i];
        int s = srcv[i];
        int b = d >> 8;
        int r = atomicAdd(&lcur[b], 1);
        pk[ebase[b] + r] = (s << 8) | (d & 255);
    }
    __syncthreads();
    int wave = t >> 6, lane = t & 63;
    for (int b = wave; b < nbuck; b += 4) {
        int c = hist[b];
        int lb = ebase[b];
        int gb = gbase[b];
        for (int j = lane; j < c; j += 64) staged[gb + j] = pk[lb + j];
    }
}

// ---------------- bucket-offset scan (nbuck <= 256) ----------------

__global__ __launch_bounds__(TPB) void k_boff(const int* __restrict__ gcur, int nbuck,
                                              int* __restrict__ bucket_off) {
    __shared__ int r[TPB];
    int t = threadIdx.x;
    int v = (t < nbuck) ? gcur[t] : 0;
    r[t] = v;
    __syncthreads();
    for (int off = 1; off < TPB; off <<= 1) {
        int u = (t >= off) ? r[t - off] : 0;
        __syncthreads();
        r[t] += u;
        __syncthreads();
    }
    if (t < nbuck) bucket_off[t] = r[t] - v;
}

// ---------------- pass B: per-bucket node sort + csr_off + dinv ----------------

__global__ __launch_bounds__(TPB) void k_passB(const int* __restrict__ staged,
                                               const int* __restrict__ gcur,
                                               const int* __restrict__ bucket_off,
                                               int* __restrict__ csr_off,
                                               int* __restrict__ csr_src,
                                               float* __restrict__ dinv,
                                               int n, int nbuck) {
    __shared__ int pk[BCAP];
    __shared__ int hist[256];
    __shared__ int nbase[256];
    __shared__ int cur[256];
    int b = blockIdx.x;
    int n0 = b << 8;
    int n1 = n0 + 256; if (n1 > n) n1 = n;
    int cnt = gcur[b];
    int base = bucket_off[b];
    int t = threadIdx.x;

    hist[t] = 0; cur[t] = 0;
    for (int i = t; i < cnt; i += TPB) pk[i] = staged[b * BCAP + i];
    __syncthreads();
    for (int i = t; i < cnt; i += TPB) atomicAdd(&hist[pk[i] & 255], 1);
    __syncthreads();
    int v = hist[t];
    nbase[t] = v;
    __syncthreads();
    for (int off = 1; off < 256; off <<= 1) {
        int u = (t >= off) ? nbase[t - off] : 0;
        __syncthreads();
        nbase[t] += u;
        __syncthreads();
    }
    nbase[t] -= v;
    if (n0 + t < n1) {
        csr_off[n0 + t] = base + nbase[t];
        dinv[n0 + t] = rsqrtf((float)(v + 1));   // +1 self loop
    }
    if (b == nbuck - 1 && t == 0) csr_off[n] = base + cnt;
    __syncthreads();
    for (int i = t; i < cnt; i += TPB) {
        int p = pk[i];
        int dloc = p & 255;
        int r = atomicAdd(&cur[dloc], 1);
        csr_src[base + nbase[dloc] + r] = p >> 8;
    }
}

// ---------------- GEMM: C[r][j] = dinv[r] * sum_k A[r][k] * W[k][j], j in [0,64) ----------------

template <int K>
__global__ __launch_bounds__(TPB) void k_gemm_scaled(const float* __restrict__ A,
                                                     const float* __restrict__ W,
                                                     const float* __restrict__ dinv,
                                                     float* __restrict__ C, int n) {
    __shared__ __align__(16) float Wc[64 * 64];
    __shared__ __align__(16) float xr[64 * 68];
    const int t = threadIdx.x;
    const int wave = t >> 6, lane = t & 63;
    const int li = lane >> 4, lj = lane & 15;
    const int rl0 = wave * 16 + li * 4;
    const int rbase = blockIdx.x * 64;

    float acc[4][4] = {{0.f,0.f,0.f,0.f},{0.f,0.f,0.f,0.f},{0.f,0.f,0.f,0.f},{0.f,0.f,0.f,0.f}};

    for (int kc = 0; kc < K; kc += 64) {
        {
            const float4* wsv = (const float4*)(W + (size_t)kc * 64);
            float4* wd = (float4*)Wc;
#pragma unroll
            for (int q = 0; q < 4; q++) wd[t + q * 256] = wsv[t + q * 256];
        }
        {
            int rl = t >> 2;
            int kq = (t & 3) * 16;
            int r = rbase + rl;
#pragma unroll
            for (int m = 0; m < 16; m += 4) {
                float4 xv;
                if (r < n) xv = *(const float4*)&A[(size_t)r * K + kc + kq + m];
                else       xv = make_float4(0.f, 0.f, 0.f, 0.f);
                *(float4*)&xr[rl * 68 + kq + m] = xv;
            }
        }
        __syncthreads();
#pragma unroll 8
        for (int kk = 0; kk < 64; kk++) {
            float4 wv = *(const float4*)&Wc[kk * 64 + lj * 4];
            float x0 = xr[(rl0 + 0) * 68 + kk];
            float x1 = xr[(rl0 + 1) * 68 + kk];
            float x2 = xr[(rl0 + 2) * 68 + kk];
            float x3 = xr[(rl0 + 3) * 68 + kk];
            acc[0][0] += x0 * wv.x; acc[0][1] += x0 * wv.y; acc[0][2] += x0 * wv.z; acc[0][3] += x0 * wv.w;
            acc[1][0] += x1 * wv.x; acc[1][1] += x1 * wv.y; acc[1][2] += x1 * wv.z; acc[1][3] += x1 * wv.w;
            acc[2][0] += x2 * wv.x; acc[2][1] += x2 * wv.y; acc[2][2] += x2 * wv.z; acc[2][3] += x2 * wv.w;
            acc[3][0] += x3 * wv.x; acc[3][1] += x3 * wv.y; acc[3][2] += x3 * wv.z; acc[3][3] += x3 * wv.w;
        }
        __syncthreads();
    }

#pragma unroll
    for (int ri = 0; ri < 4; ri++) {
        int r = rbase + rl0 + ri;
        if (r < n) {
            float d = dinv[r];
            float4 o = make_float4(acc[ri][0] * d, acc[ri][1] * d, acc[ri][2] * d, acc[ri][3] * d);
            *(float4*)&C[(size_t)r * 64 + lj * 4] = o;
        }
    }
}

// ---------------- Aggregation (CSR gather), 8 rows in flight ----------------

__global__ __launch_bounds__(TPB) void k_agg(const float* __restrict__ hs,
                                             const int* __restrict__ csr_off,
                                             const int* __restrict__ csr_src,
                                             const float* __restrict__ dinv,
                                             const float* __restrict__ bias,
                                             float* __restrict__ out, int n) {
    int node = blockIdx.x * 4 + (threadIdx.x >> 6);
    int lane = threadIdx.x & 63;
    if (node >= n) return;
    int p0 = csr_off[node];
    int p1 = csr_off[node + 1];
    float acc = hs[(size_t)node * 64 + lane];  // self loop
    int p = p0;
    for (; p + 8 <= p1; p += 8) {
        int s0 = csr_src[p + 0];
        int s1 = csr_src[p + 1];
        int s2 = csr_src[p + 2];
        int s3 = csr_src[p + 3];
        int s4 = csr_src[p + 4];
        int s5 = csr_src[p + 5];
        int s6 = csr_src[p + 6];
        int s7 = csr_src[p + 7];
        float a0 = hs[(size_t)s0 * 64 + lane];
        float a1 = hs[(size_t)s1 * 64 + lane];
        float a2 = hs[(size_t)s2 * 64 + lane];
        float a3 = hs[(size_t)s3 * 64 + lane];
        float a4 = hs[(size_t)s4 * 64 + lane];
        float a5 = hs[(size_t)s5 * 64 + lane];
        float a6 = hs[(size_t)s6 * 64 + lane];
        float a7 = hs[(size_t)s7 * 64 + lane];
        acc += ((a0 + a1) + (a2 + a3)) + ((a4 + a5) + (a6 + a7));
    }
    for (; p < p1; p++) acc += hs[(size_t)csr_src[p] * 64 + lane];
    float v = dinv[node] * acc + bias[lane];
    out[(size_t)node * 64 + lane] = fmaxf(v, 0.f);
}

// ---------------- Pool: sorted batch; uniform-chunk fast path ----------------

__global__ __launch_bounds__(TPB) void k_pool(const float* __restrict__ h,
                                              const int* __restrict__ batch, int n,
                                              float* __restrict__ gsum,
                                              int* __restrict__ gcnt) {
    const int CH = 16;
    int wid = blockIdx.x * 4 + (threadIdx.x >> 6);
    int lane = threadIdx.x & 63;
    int i0 = wid * CH;
    if (i0 >= n) return;
    int i1 = i0 + CH; if (i1 > n) i1 = n;
    int g0 = batch[i0];
    int g1 = batch[i1 - 1];
    if (g0 == g1) {
        float acc = 0.f;
#pragma unroll
        for (int i = 0; i < CH; i++) {
            int idx = i0 + i;
            if (idx < i1) acc += h[(size_t)idx * 64 + lane];
        }
        atomicAdd(&gsum[g0 * 64 + lane], acc);
        if (lane == 0) atomicAdd(&gcnt[g0], i1 - i0);
    } else {
        int cur = g0;
        float acc = 0.f;
        int cnt = 0;
        for (int i = i0; i < i1; i++) {
            int g = batch[i];
            if (g != cur) {
                atomicAdd(&gsum[cur * 64 + lane], acc);
                if (lane == 0) atomicAdd(&gcnt[cur], cnt);
                acc = 0.f; cnt = 0; cur = g;
            }
            acc += h[(size_t)i * 64 + lane];
            cnt++;
        }
        atomicAdd(&gsum[cur * 64 + lane], acc);
        if (lane == 0) atomicAdd(&gcnt[cur], cnt);
    }
}

// ---------------- Head, stage 1: z[g][o] = relu(pooled[g]@fc1[:,o] + fc1b[o]) ----------------
// 32 blocks x 256: thread -> (g = blk*2 + t>>7, o = t&127). fc1w coalesced.

__global__ __launch_bounds__(TPB) void k_head1(const float* __restrict__ gsum,
                                               const int* __restrict__ gcnt,
                                               const float* __restrict__ fc1w,
                                               const float* __restrict__ fc1b,
                                               float* __restrict__ z) {
    int t = threadIdx.x;
    int g = blockIdx.x * 2 + (t >> 7);
    int o = t & 127;
    int c = gcnt[g]; if (c < 1) c = 1;
    float inv = 1.0f / (float)c;
    float a = fc1b[o];
#pragma unroll 16
    for (int j = 0; j < 64; j++) {
        float pj = gsum[g * 64 + j] * inv;
        a += pj * fc1w[j * 128 + o];
    }
    z[g * 128 + o] = fmaxf(a, 0.f);
}

// ---------------- Head, stage 2: out[g][c] = z[g]@fc2[:,c] + fc2b[c] ----------------

__global__ __launch_bounds__(TPB) void k_head2(const float* __restrict__ z,
                                               const float* __restrict__ fc2w,
                                               const float* __restrict__ fc2b,
                                               float* __restrict__ out) {
    int t = threadIdx.x;
    int g = t >> 2, c = t & 3;
    float a = fc2b[c];
#pragma unroll 16
    for (int o = 0; o < 128; o++) a += z[g * 128 + o] * fc2w[o * 4 + c];
    out[t] = a;
}

// ---------------- launch ----------------

extern "C" void kernel_launch(void* const* d_in, const int* in_sizes, int n_in,
                              void* d_out, int out_size, void* d_ws, size_t ws_size,
                              hipStream_t stream) {
    const float* x    = (const float*)d_in[0];
    const int*   ei   = (const int*)d_in[1];
    const int*   batch= (const int*)d_in[2];
    const float* W1   = (const float*)d_in[3];
    const float* b1   = (const float*)d_in[4];
    const float* W2   = (const float*)d_in[5];
    const float* b2   = (const float*)d_in[6];
    const float* fc1w = (const float*)d_in[7];
    const float* fc1b = (const float*)d_in[8];
    const float* fc2w = (const float*)d_in[9];
    const float* fc2b = (const float*)d_in[10];

    const int n = in_sizes[2];        // 50000
    const int E = in_sizes[1] / 2;    // 800000
    const int* srcv = ei;
    const int* dstv = ei + E;
    const int nbuck = (n + 255) >> 8; // 196 (must be <= 256)

    // workspace carve; zeroed region contiguous at front
    char* w = (char*)d_ws;
    int*   gcur   = (int*)w;            w += 256 * 4;
    int*   gcnt   = (int*)w;            w += 64 * 4;
    float* gsum   = (float*)w;          w += 64 * 64 * 4;
    size_t zbytes = (size_t)w - (size_t)d_ws;
    int*   bucket_off = (int*)w;        w += 256 * 4;
    int*   csr_off= (int*)w;            w += (size_t)(n + 1) * 4;
    float* dinv   = (float*)w;          w += (size_t)n * 4;
    int*   csr_src= (int*)w;            w += (size_t)E * 4;
    int*   staged = (int*)w;            w += (size_t)nbuck * BCAP * 4;
    float* zbuf   = (float*)w;          w += 64 * 128 * 4;
    w = (char*)(((size_t)w + 255) & ~(size_t)255);
    float* hs = (float*)w;              w += (size_t)n * 64 * 4;
    float* hb = (float*)w;              w += (size_t)n * 64 * 4;

    hipMemsetAsync(d_ws, 0, zbytes, stream);

    int gA = (E + CHUNK_A - 1) / CHUNK_A;   // 196
    k_passA<<<gA, TPB, 0, stream>>>(srcv, dstv, E, gcur, staged, nbuck);
    k_boff<<<1, TPB, 0, stream>>>(gcur, nbuck, bucket_off);
    k_passB<<<nbuck, TPB, 0, stream>>>(staged, gcur, bucket_off, csr_off, csr_src,
                                       dinv, n, nbuck);

    int gRows = (n + 63) / 64;
    int gNode = (n + 3) / 4;
    k_gemm_scaled<256><<<gRows, TPB, 0, stream>>>(x, W1, dinv, hs, n);
    k_agg<<<gNode, TPB, 0, stream>>>(hs, csr_off, csr_src, dinv, b1, hb, n);
    k_gemm_scaled<64><<<gRows, TPB, 0, stream>>>(hb, W2, dinv, hs, n);
    k_agg<<<gNode, TPB, 0, stream>>>(hs, csr_off, csr_src, dinv, b2, hb, n);

    int nwaves16 = (n + 15) / 16;
    k_pool<<<(nwaves16 + 3) / 4, TPB, 0, stream>>>(hb, batch, n, gsum, gcnt);
    k_head1<<<32, TPB, 0, stream>>>(gsum, gcnt, fc1w, fc1b, zbuf);
    k_head2<<<1, TPB, 0, stream>>>(zbuf, fc2w, fc2b, (float*)d_out);
}